// Round 1
// 586.820 us; speedup vs baseline: 1.0245x; 1.0245x over previous
//
#include <hip/hip_runtime.h>
#include <hip/hip_bf16.h>
#include <cstdint>
#include <cstddef>

#define DIM 1024
#define B_SZ 32
#define L_SZ 2048

#define BM 128
#define BN 128

// pre_kernel block-range split
#define CVT_BLOCKS 8192
#define HT_BLOCKS  512
#define WA_BLOCKS  512

typedef __attribute__((ext_vector_type(8))) short bf16x8;
typedef __attribute__((ext_vector_type(4))) float floatx4;

static __device__ __forceinline__ unsigned cvt2_bf16_rne(float a, float b) {
    unsigned ua = __builtin_bit_cast(unsigned, a);
    unsigned ub = __builtin_bit_cast(unsigned, b);
    ua = (ua + 0x7FFFu + ((ua >> 16) & 1u)) >> 16;
    ub = (ub + 0x7FFFu + ((ub >> 16) & 1u)) >> 16;
    return ua | (ub << 16);
}

static __device__ __forceinline__ float bf2f(unsigned u16) {
    return __builtin_bit_cast(float, u16 << 16);
}

// tanh(x) = 1 - 2/(e^{2x}+1)
static __device__ __forceinline__ float tanh_fast(float x) {
    float e = __expf(2.0f * x);
    return 1.0f - 2.0f * __builtin_amdgcn_rcpf(e + 1.0f);
}

// async global->LDS, 16B per lane; LDS dest = uniform base + lane*16
static __device__ __forceinline__ void gld_lds16(const void* g, void* lds) {
    __builtin_amdgcn_global_load_lds(
        (const __attribute__((address_space(1))) unsigned int*)g,
        (__attribute__((address_space(3))) unsigned int*)lds,
        16, 0, 0);
}

#define VMCNT(n) asm volatile("s_waitcnt vmcnt(" #n ")" ::: "memory")
#define BARRIER() __builtin_amdgcn_s_barrier()

// ---------------------------------------------------------------------------
// pre_kernel: ONE dispatch for {ctx fp32->bf16, ht_proj, Wa_s fp32->bf16,
// scores zero, weighted zero}. Branch is block-uniform (blockIdx split).
// (UNCHANGED this round: isolate the GEMM restructure for attribution.)
// ---------------------------------------------------------------------------
__global__ __launch_bounds__(256) void pre_kernel(
    const float* __restrict__ x, const float* __restrict__ ctx,
    const float* __restrict__ Wa,
    unsigned short* __restrict__ ctxB, unsigned short* __restrict__ WaB,
    float* __restrict__ ht, float* __restrict__ scores,
    float* __restrict__ weighted)
{
    const int bid = blockIdx.x, t = threadIdx.x;

    if (bid < CVT_BLOCKS) {
        const long n8 = (long)B_SZ * L_SZ * DIM / 8;
        const long stride = (long)CVT_BLOCKS * 256;
        for (long i = (long)bid * 256 + t; i < n8; i += stride) {
            const float4 a = ((const float4*)ctx)[i * 2];
            const float4 b = ((const float4*)ctx)[i * 2 + 1];
            uint4 o;
            o.x = cvt2_bf16_rne(a.x, a.y);
            o.y = cvt2_bf16_rne(a.z, a.w);
            o.z = cvt2_bf16_rne(b.x, b.y);
            o.w = cvt2_bf16_rne(b.z, b.w);
            ((uint4*)ctxB)[i] = o;
        }
    } else if (bid < CVT_BLOCKS + HT_BLOCKS) {
        const int lb = bid - CVT_BLOCKS;
        const int gi = lb * 256 + t;
        if (gi < B_SZ * L_SZ) scores[gi] = 0.f;
        const int b = lb >> 4, kb = lb & 15;
        __shared__ float xs[DIM];
        for (int i = t; i < DIM; i += 256) xs[i] = x[b * DIM + i];
        __syncthreads();
        const int wave = t >> 6, lane = t & 63;
        const float4* xs4 = (const float4*)xs;
        for (int kk = 0; kk < 16; ++kk) {
            const int k = kb * 64 + wave * 16 + kk;
            const float4* wr = (const float4*)(Wa + (size_t)k * (2 * DIM));
            float s = 0.f;
            #pragma unroll
            for (int d = 0; d < DIM / 4; d += 64) {
                const float4 w4 = wr[d + lane];
                const float4 x4 = xs4[d + lane];
                s += w4.x * x4.x + w4.y * x4.y + w4.z * x4.z + w4.w * x4.w;
            }
            #pragma unroll
            for (int off = 32; off > 0; off >>= 1) s += __shfl_xor(s, off);
            if (lane == 0) ht[b * DIM + k] = s;
        }
    } else {
        const int lb = bid - CVT_BLOCKS - HT_BLOCKS;
        const int i = lb * 256 + t;
        if (i < B_SZ * DIM) weighted[i] = 0.f;
        const int k = i >> 7, dc = i & 127;
        const float* s = Wa + (size_t)k * (2 * DIM) + DIM + dc * 8;
        const float4 a = ((const float4*)s)[0];
        const float4 b4 = ((const float4*)s)[1];
        uint4 o;
        o.x = cvt2_bf16_rne(a.x, a.y);
        o.y = cvt2_bf16_rne(a.z, a.w);
        o.z = cvt2_bf16_rne(b4.x, b4.y);
        o.w = cvt2_bf16_rne(b4.z, b4.w);
        ((uint4*)(WaB + (size_t)k * DIM + dc * 8))[0] = o;
    }
}

// ---------------------------------------------------------------------------
// 8-phase 256x256xBK64 bf16 GEMM + fused tanh/Va epilogue (T1+T2+T3+T4+T5).
// 8 waves rotate over C-quadrants: phase = one quadrant x K=64 (16 MFMA/wave).
// LDS 128KB: [dbuf][half] x (A,B), each half 128rows x 64cols, XOR
// chunk-swizzled (same proven swizzle as the previous 128^2 kernel: 0 bank
// conflicts). Staging: 1 half-tile (2 x global_load_lds/thread) per phase into
// the slot that went dead >=1 phase ago; counted vmcnt(2)@ph4 / vmcnt(4)@ph8
// ONLY (never 0 in steady state) keeps 2-3 half-tiles in flight across raw
// s_barrier (NOT __syncthreads -- that drains vmcnt and kills the pipeline).
// Slot lifetime / landing-deadline bookkeeping verified per half-tile.
// ---------------------------------------------------------------------------
static __device__ __forceinline__ void frag_loads_a(
    const unsigned short* sh, int wr, int l15, int quad, bf16x8 (&af)[4][2])
{
    #pragma unroll
    for (int i = 0; i < 4; ++i) {
        const int r = wr + i * 16 + l15;
        #pragma unroll
        for (int kb = 0; kb < 2; ++kb) {
            const int c = (kb * 4 + quad) ^ (r & 7);
            af[i][kb] = *(const bf16x8*)&sh[r * 64 + c * 8];
        }
    }
}

static __device__ __forceinline__ void frag_loads_b(
    const unsigned short* sh, int wc, int l15, int quad, bf16x8 (&bv)[2][2])
{
    #pragma unroll
    for (int j = 0; j < 2; ++j) {
        const int r = wc + j * 16 + l15;
        #pragma unroll
        for (int kb = 0; kb < 2; ++kb) {
            const int c = (kb * 4 + quad) ^ (r & 7);
            bv[j][kb] = *(const bf16x8*)&sh[r * 64 + c * 8];
        }
    }
}

static __device__ __forceinline__ void mma16(
    floatx4 (&acc)[4][2], const bf16x8 (&af)[4][2], const bf16x8 (&bv)[2][2])
{
    __builtin_amdgcn_s_setprio(1);
    #pragma unroll
    for (int kb = 0; kb < 2; ++kb)
        #pragma unroll
        for (int i = 0; i < 4; ++i)
            #pragma unroll
            for (int j = 0; j < 2; ++j)
                acc[i][j] = __builtin_amdgcn_mfma_f32_16x16x32_bf16(
                    af[i][kb], bv[j][kb], acc[i][j], 0, 0, 0);
    __builtin_amdgcn_s_setprio(0);
}

// stage one half-tile (128 rows x 64 cols bf16 = 16KB) = 2 gld_lds16/thread.
// LDS dest linear in thread order (wave-uniform base); swizzle applied on the
// GLOBAL source chunk (lc = (ch&7) ^ (lr&7)) so reads can use the same XOR.
static __device__ __forceinline__ void stage_half(
    const unsigned short* __restrict__ g, unsigned short* lds, int t, int wave)
{
    #pragma unroll
    for (int q = 0; q < 2; ++q) {
        const int ch = q * 512 + t;
        const int lr = ch >> 3;
        const int lc = (ch & 7) ^ (lr & 7);
        gld_lds16(g + (size_t)lr * DIM + lc * 8, lds + (q * 512 + wave * 64) * 8);
    }
}

__global__ __launch_bounds__(512, 2) void gemm_score_8ph(
    const unsigned short* __restrict__ A, const unsigned short* __restrict__ Bm,
    const float* __restrict__ Va, const float* __restrict__ ht,
    float* __restrict__ scores)
{
    __shared__ __align__(16) unsigned short As[2][2][128 * 64];
    __shared__ __align__(16) unsigned short Bs[2][2][128 * 64];

    // T1: XCD-aware swizzle. 1024 blocks, xcd = bid%8 (round-robin assumption);
    // give each XCD 128 contiguous logical tiles so the 4 n-blocks sharing an
    // A-panel (same by) land on ONE XCD L2.
    const int bid = blockIdx.x;
    const int logical = (bid & 7) * 128 + (bid >> 3);   // bijective
    const int m0 = (logical >> 2) * 256;                // 256 m-tiles
    const int n0 = (logical & 3) * 256;                 // 4 n-tiles

    const int t = threadIdx.x;
    const int lane = t & 63, wave = t >> 6;
    const int l15 = lane & 15, quad = lane >> 4;
    const int wr = (wave >> 2) * 64;   // row group within 128-row quadrant half
    const int wc = (wave & 3) * 32;    // col group within 128-col quadrant half

    const unsigned short* Ag = A + (size_t)m0 * DIM;
    const unsigned short* Bg = Bm + (size_t)n0 * DIM;

    floatx4 acc[4][4][2];   // [quadrant][i][j]
    #pragma unroll
    for (int q = 0; q < 4; ++q)
        #pragma unroll
        for (int i = 0; i < 4; ++i)
            #pragma unroll
            for (int j = 0; j < 2; ++j) acc[q][i][j] = (floatx4)0.f;

    bf16x8 af[4][2], bv[2][2];

    // prologue: tile0 all 4 halves (buf0) + tile1 Ah0,Bh1 (buf1). vmcnt(4)
    // leaves the 2 buf1 stages in flight, guarantees buf0 fully landed.
    stage_half(Ag, &As[0][0][0], t, wave);
    stage_half(Bg, &Bs[0][0][0], t, wave);
    stage_half(Bg + (size_t)128 * DIM, &Bs[0][1][0], t, wave);
    stage_half(Ag + (size_t)128 * DIM, &As[0][1][0], t, wave);
    stage_half(Ag + 64, &As[1][0][0], t, wave);
    stage_half(Bg + (size_t)128 * DIM + 64, &Bs[1][1][0], t, wave);
    VMCNT(4);
    BARRIER();

    for (int it = 0; it < 8; ++it) {            // 2 K-tiles (BK=64) per iter
        const int k1 = (2 * it + 1) * 64;
        const int k2 = (2 * it + 2) * 64;
        const int k3 = (2 * it + 3) * 64;
        const bool more = (it < 7);

        // ph1: q=(0,0) from buf0; stage buf1.Bh0,buf1.Ah1 <- tile a+1
        frag_loads_a(&As[0][0][0], wr, l15, quad, af);
        frag_loads_b(&Bs[0][0][0], wc, l15, quad, bv);
        stage_half(Bg + k1, &Bs[1][0][0], t, wave);
        stage_half(Ag + (size_t)128 * DIM + k1, &As[1][1][0], t, wave);
        BARRIER();
        mma16(acc[0], af, bv);
        BARRIER();

        // ph2: q=(0,1) (af reused)
        frag_loads_b(&Bs[0][1][0], wc, l15, quad, bv);
        BARRIER();
        mma16(acc[1], af, bv);
        BARRIER();

        // ph3: q=(1,1) (bv reused)
        frag_loads_a(&As[0][1][0], wr, l15, quad, af);
        BARRIER();
        mma16(acc[3], af, bv);
        BARRIER();

        // ph4: q=(1,0); stage buf0.Ah0 <- a+2; vmcnt(2) guarantees all of
        // tile a+1 (buf1) has landed before ph5-8 read it.
        frag_loads_b(&Bs[0][0][0], wc, l15, quad, bv);
        if (more) { stage_half(Ag + k2, &As[0][0][0], t, wave); VMCNT(2); }
        else      { VMCNT(0); }
        BARRIER();
        mma16(acc[2], af, bv);
        BARRIER();

        // ph5: q=(0,0) from buf1; stage buf0.Bh1 <- a+2
        frag_loads_a(&As[1][0][0], wr, l15, quad, af);
        frag_loads_b(&Bs[1][0][0], wc, l15, quad, bv);
        if (more) stage_half(Bg + (size_t)128 * DIM + k2, &Bs[0][1][0], t, wave);
        BARRIER();
        mma16(acc[0], af, bv);
        BARRIER();

        // ph6: q=(0,1); stage buf0.Ah1 <- a+2
        frag_loads_b(&Bs[1][1][0], wc, l15, quad, bv);
        if (more) stage_half(Ag + (size_t)128 * DIM + k2, &As[0][1][0], t, wave);
        BARRIER();
        mma16(acc[1], af, bv);
        BARRIER();

        // ph7: q=(1,1); stage buf0.Bh0 <- a+2, then buf1.Ah0 <- a+3
        frag_loads_a(&As[1][1][0], wr, l15, quad, af);
        if (more) {
            stage_half(Bg + k2, &Bs[0][0][0], t, wave);
            stage_half(Ag + k3, &As[1][0][0], t, wave);
        }
        BARRIER();
        mma16(acc[3], af, bv);
        BARRIER();

        // ph8: q=(1,0); stage buf1.Bh1 <- a+3; vmcnt(4) guarantees all of
        // tile a+2 (buf0) landed before next iter ph1-4 read it (leaves the
        // 2 newest buf1 stages in flight).
        frag_loads_b(&Bs[1][0][0], wc, l15, quad, bv);
        if (more) {
            stage_half(Bg + (size_t)128 * DIM + k3, &Bs[1][1][0], t, wave);
            VMCNT(4);
        }
        BARRIER();
        mma16(acc[2], af, bv);
        BARRIER();
    }

    // epilogue: scores[m] += sum_n tanh(acc + ht[n]) * Va[n]
    // C/D layout: n = lane&15, m = quad*4 + reg (proven on the 128^2 kernel)
    const int bb = m0 >> 11;
    float htv[2][2], vav[2][2];
    #pragma unroll
    for (int qc = 0; qc < 2; ++qc)
        #pragma unroll
        for (int j = 0; j < 2; ++j) {
            const int ng = n0 + qc * 128 + wc + j * 16 + l15;
            htv[qc][j] = ht[bb * DIM + ng];
            vav[qc][j] = Va[ng];
        }
    #pragma unroll
    for (int qr = 0; qr < 2; ++qr)
        #pragma unroll
        for (int i = 0; i < 4; ++i)
            #pragma unroll
            for (int r = 0; r < 4; ++r) {
                float s = 0.f;
                #pragma unroll
                for (int qc = 0; qc < 2; ++qc)
                    #pragma unroll
                    for (int j = 0; j < 2; ++j)
                        s += tanh_fast(acc[qr * 2 + qc][i][j][r] + htv[qc][j]) * vav[qc][j];
                s += __shfl_xor(s, 8);
                s += __shfl_xor(s, 4);
                s += __shfl_xor(s, 2);
                s += __shfl_xor(s, 1);
                if (l15 == 0)
                    atomicAdd(&scores[m0 + qr * 128 + wr + i * 16 + quad * 4 + r], s);
            }
}

// ---------------------------------------------------------------------------
// post_kernel: softmax (stats recomputed per block -- deterministic) + attn
// slice write + weighted slice accumulate from bf16 ctx. (UNCHANGED.)
// ---------------------------------------------------------------------------
__global__ __launch_bounds__(256) void post_kernel(
    const float* __restrict__ scores, const unsigned short* __restrict__ ctxB,
    float* __restrict__ attn, float* __restrict__ weighted)
{
    const int b = blockIdx.x, slice = blockIdx.y, t = threadIdx.x;
    const float* sc = scores + b * L_SZ;
    __shared__ float red[256];
    __shared__ float att[128];

    float m = -1e30f;
    for (int l = t; l < L_SZ; l += 256) m = fmaxf(m, sc[l]);
    red[t] = m; __syncthreads();
    for (int s = 128; s > 0; s >>= 1) { if (t < s) red[t] = fmaxf(red[t], red[t + s]); __syncthreads(); }
    m = red[0]; __syncthreads();
    float sum = 0.f;
    for (int l = t; l < L_SZ; l += 256) sum += __expf(sc[l] - m);
    red[t] = sum; __syncthreads();
    for (int s = 128; s > 0; s >>= 1) { if (t < s) red[t] += red[t + s]; __syncthreads(); }
    const float inv = 1.0f / red[0];

    const int l0 = slice * 128;
    if (t < 128) {
        const float av = __expf(sc[l0 + t] - m) * inv;
        att[t] = av;
        attn[b * L_SZ + l0 + t] = av;
    }
    __syncthreads();

    const unsigned short* cb = ctxB + ((size_t)b * L_SZ + l0) * DIM + t * 4;
    float a0 = 0.f, a1 = 0.f, a2 = 0.f, a3 = 0.f;
    for (int l = 0; l < 128; ++l) {
        const float a = att[l];
        const uint2 v = *(const uint2*)(cb + (size_t)l * DIM);
        a0 += a * bf2f(v.x & 0xFFFFu);
        a1 += a * bf2f(v.x >> 16);
        a2 += a * bf2f(v.y & 0xFFFFu);
        a3 += a * bf2f(v.y >> 16);
    }
    float* o = weighted + b * DIM + t * 4;
    atomicAdd(o + 0, a0);
    atomicAdd(o + 1, a1);
    atomicAdd(o + 2, a2);
    atomicAdd(o + 3, a3);
}

// ---------------------------------------------------------------------------
// fallback path (ws too small): fp32-staging GEMM + separate aux kernels
// ---------------------------------------------------------------------------
#define LDS_STRIDE 40
__global__ __launch_bounds__(256) void ht_kernel_fb(const float* __restrict__ x,
                                                    const float* __restrict__ Wa,
                                                    float* __restrict__ ht,
                                                    float* __restrict__ scores,
                                                    float* __restrict__ weighted) {
    const int b = blockIdx.x, kb = blockIdx.y, t = threadIdx.x;
    const int gidx = (b * 16 + kb) * 256 + t;
    if (gidx < B_SZ * L_SZ) scores[gidx] = 0.f;
    if (gidx < B_SZ * DIM) weighted[gidx] = 0.f;
    __shared__ float xs[DIM];
    for (int i = t; i < DIM; i += 256) xs[i] = x[b * DIM + i];
    __syncthreads();
    const int wave = t >> 6, lane = t & 63;
    for (int kk = 0; kk < 16; ++kk) {
        const int k = kb * 64 + wave * 16 + kk;
        const float* wr = Wa + (size_t)k * (2 * DIM);
        float s = 0.f;
        #pragma unroll
        for (int d = 0; d < DIM; d += 64) s += xs[d + lane] * wr[d + lane];
        #pragma unroll
        for (int off = 32; off > 0; off >>= 1) s += __shfl_xor(s, off);
        if (lane == 0) ht[b * DIM + k] = s;
    }
}

__global__ __launch_bounds__(256, 2) void gemm_score_kernel(
    const float* __restrict__ ctx, const float* __restrict__ Wa,
    const float* __restrict__ Va, const float* __restrict__ ht,
    float* __restrict__ scores)
{
    __shared__ unsigned short As[BM * LDS_STRIDE];
    __shared__ unsigned short Bs[BN * LDS_STRIDE];
    const int t = threadIdx.x;
    const int n0 = blockIdx.x * BN;
    const int m0 = blockIdx.y * BM;
    const int lane = t & 63, wave = t >> 6;
    const int l15 = lane & 15, quad = lane >> 4;
    const int wm = (wave >> 1) * 64, wn = (wave & 1) * 64;
    const int srow = t >> 3;
    const int scol = (t & 7) * 4;
    const float* aBase = ctx + (size_t)(m0 + srow) * DIM + scol;
    const float* bBase = Wa + (size_t)(n0 + srow) * (2 * DIM) + DIM + scol;

    floatx4 acc[4][4];
    #pragma unroll
    for (int i = 0; i < 4; ++i)
        #pragma unroll
        for (int j = 0; j < 4; ++j) acc[i][j] = (floatx4)0.f;

    for (int k0 = 0; k0 < DIM; k0 += 32) {
        __syncthreads();
        #pragma unroll
        for (int r = 0; r < 4; ++r) {
            const float4 va = *(const float4*)(aBase + (size_t)(r * 32) * DIM + k0);
            const float4 vb = *(const float4*)(bBase + (size_t)(r * 32) * (2 * DIM) + k0);
            *(uint2*)&As[(srow + r * 32) * LDS_STRIDE + scol] =
                make_uint2(cvt2_bf16_rne(va.x, va.y), cvt2_bf16_rne(va.z, va.w));
            *(uint2*)&Bs[(srow + r * 32) * LDS_STRIDE + scol] =
                make_uint2(cvt2_bf16_rne(vb.x, vb.y), cvt2_bf16_rne(vb.z, vb.w));
        }
        __syncthreads();
        bf16x8 af[4], bfr[4];
        #pragma unroll
        for (int i = 0; i < 4; ++i)
            af[i] = *(const bf16x8*)&As[(wm + i * 16 + l15) * LDS_STRIDE + quad * 8];
        #pragma unroll
        for (int j = 0; j < 4; ++j)
            bfr[j] = *(const bf16x8*)&Bs[(wn + j * 16 + l15) * LDS_STRIDE + quad * 8];
        #pragma unroll
        for (int i = 0; i < 4; ++i)
            #pragma unroll
            for (int j = 0; j < 4; ++j)
                acc[i][j] = __builtin_amdgcn_mfma_f32_16x16x32_bf16(af[i], bfr[j], acc[i][j], 0, 0, 0);
    }
    const int bb = m0 >> 11;
    float htv[4], vav[4];
    #pragma unroll
    for (int j = 0; j < 4; ++j) {
        const int ng = n0 + wn + j * 16 + l15;
        htv[j] = ht[bb * DIM + ng];
        vav[j] = Va[ng];
    }
    #pragma unroll
    for (int i = 0; i < 4; ++i) {
        #pragma unroll
        for (int r = 0; r < 4; ++r) {
            float s = 0.f;
            #pragma unroll
            for (int j = 0; j < 4; ++j)
                s += tanh_fast(acc[i][j][r] + htv[j]) * vav[j];
            s += __shfl_xor(s, 8);
            s += __shfl_xor(s, 4);
            s += __shfl_xor(s, 2);
            s += __shfl_xor(s, 1);
            if (l15 == 0)
                atomicAdd(&scores[m0 + wm + i * 16 + quad * 4 + r], s);
        }
    }
}

__global__ __launch_bounds__(256) void post_kernel_fb(
    const float* __restrict__ scores, const float* __restrict__ ctx,
    float* __restrict__ attn, float* __restrict__ weighted)
{
    const int b = blockIdx.x, slice = blockIdx.y, t = threadIdx.x;
    const float* sc = scores + b * L_SZ;
    __shared__ float red[256];
    __shared__ float att[128];
    float m = -1e30f;
    for (int l = t; l < L_SZ; l += 256) m = fmaxf(m, sc[l]);
    red[t] = m; __syncthreads();
    for (int s = 128; s > 0; s >>= 1) { if (t < s) red[t] = fmaxf(red[t], red[t + s]); __syncthreads(); }
    m = red[0]; __syncthreads();
    float sum = 0.f;
    for (int l = t; l < L_SZ; l += 256) sum += __expf(sc[l] - m);
    red[t] = sum; __syncthreads();
    for (int s = 128; s > 0; s >>= 1) { if (t < s) red[t] += red[t + s]; __syncthreads(); }
    const float inv = 1.0f / red[0];
    const int l0 = slice * 128;
    if (t < 128) {
        const float av = __expf(sc[l0 + t] - m) * inv;
        att[t] = av;
        attn[b * L_SZ + l0 + t] = av;
    }
    __syncthreads();
    const float* cb = ctx + ((size_t)b * L_SZ + l0) * DIM + t * 4;
    float4 w = make_float4(0.f, 0.f, 0.f, 0.f);
    for (int l = 0; l < 128; ++l) {
        const float a = att[l];
        const float4 c = *(const float4*)(cb + (size_t)l * DIM);
        w.x += a * c.x; w.y += a * c.y; w.z += a * c.z; w.w += a * c.w;
    }
    float* o = weighted + b * DIM + t * 4;
    atomicAdd(o + 0, w.x);
    atomicAdd(o + 1, w.y);
    atomicAdd(o + 2, w.z);
    atomicAdd(o + 3, w.w);
}

extern "C" void kernel_launch(void* const* d_in, const int* in_sizes, int n_in,
                              void* d_out, int out_size, void* d_ws, size_t ws_size,
                              hipStream_t stream) {
    const float* x   = (const float*)d_in[0];   // 32 x 1024
    const float* ctx = (const float*)d_in[1];   // 32 x 2048 x 1024
    const float* Wa  = (const float*)d_in[2];   // 1024 x 2048
    const float* Va  = (const float*)d_in[3];   // 1 x 1024

    float* out      = (float*)d_out;
    float* weighted = out;                      // 32*1024
    float* attn     = out + B_SZ * DIM;         // 32*2048

    float* scores = (float*)d_ws;               // 256 KB
    float* ht     = scores + B_SZ * L_SZ;       // 128 KB

    const size_t base = (size_t)(B_SZ * L_SZ + B_SZ * DIM) * sizeof(float);
    const size_t need = base + (size_t)DIM * DIM * 2            // Wa_s bf16: 2 MB
                      + (size_t)B_SZ * L_SZ * DIM * 2;          // ctx bf16: 128 MB

    if (ws_size >= need) {
        unsigned short* WaB  = (unsigned short*)((char*)d_ws + base);
        unsigned short* ctxB = WaB + (size_t)DIM * DIM;
        pre_kernel<<<CVT_BLOCKS + HT_BLOCKS + WA_BLOCKS, 256, 0, stream>>>(
            x, ctx, Wa, ctxB, WaB, ht, scores, weighted);
        gemm_score_8ph<<<(B_SZ * L_SZ / 256) * (DIM / 256), 512, 0, stream>>>(
            ctxB, WaB, Va, ht, scores);
        post_kernel<<<dim3(B_SZ, 16), 256, 0, stream>>>(scores, ctxB, attn, weighted);
    } else {
        ht_kernel_fb<<<dim3(B_SZ, 16), 256, 0, stream>>>(x, Wa, ht, scores, weighted);
        gemm_score_kernel<<<dim3(DIM / BN, (B_SZ * L_SZ) / BM), 256, 0, stream>>>(
            ctx, Wa, Va, ht, scores);
        post_kernel_fb<<<dim3(B_SZ, 16), 256, 0, stream>>>(scores, ctx, attn, weighted);
    }
}